// Round 1
// baseline (302.883 us; speedup 1.0000x reference)
//
#include <hip/hip_runtime.h>

// Problem constants (from reference): x[B=16,C=64,H=224,W=224] fp32,
// dct_bases[M=16,16,16] fp32, out[B,M,H,W] fp32.
#define B_  16
#define C_  64
#define H_  224
#define W_  224
#define M_  16
#define PH  16
#define PW  16
#define HP  14   // H/PH
#define WP  14   // W/PW

__global__ __launch_bounds__(256)
void dct_patch_fused(const float* __restrict__ x,
                     const float* __restrict__ bases,
                     float* __restrict__ out) {
    const int bid = blockIdx.x;              // 0 .. B*HP*WP-1
    const int wp  = bid % WP;
    const int hp  = (bid / WP) % HP;
    const int b   = bid / (WP * HP);

    __shared__ float4 part[256];             // phase-A partials
    __shared__ float  meanp[PH * 17];        // mean patch, row stride 17 (bank pad)
    __shared__ float  coef[M_];

    const int t  = threadIdx.x;
    const int f4 = t & 63;                   // which float4 of the 16x16 patch
    const int cg = t >> 6;                   // channel group 0..3 (16 ch each)
    const int i  = f4 >> 2;                  // patch row 0..15
    const int c4 = f4 & 3;                   // float4 column group 0..3

    const size_t plane = (size_t)H_ * W_;

    // ---- Phase A: channel-mean of this 16x16 patch ----
    const float* p = x + ((size_t)b * C_ + (size_t)cg * 16) * plane
                       + (size_t)(hp * PH + i) * W_ + (size_t)(wp * PW + c4 * 4);
    float4 acc = {0.f, 0.f, 0.f, 0.f};
#pragma unroll
    for (int cc = 0; cc < 16; ++cc) {
        float4 v = *(const float4*)(p + (size_t)cc * plane);
        acc.x += v.x; acc.y += v.y; acc.z += v.z; acc.w += v.w;
    }
    part[t] = acc;
    __syncthreads();

    if (t < 64) {
        float4 a0 = part[t];
        float4 a1 = part[t + 64];
        float4 a2 = part[t + 128];
        float4 a3 = part[t + 192];
        const float inv = 1.f / (float)C_;
        meanp[i * 17 + c4 * 4 + 0] = (a0.x + a1.x + a2.x + a3.x) * inv;
        meanp[i * 17 + c4 * 4 + 1] = (a0.y + a1.y + a2.y + a3.y) * inv;
        meanp[i * 17 + c4 * 4 + 2] = (a0.z + a1.z + a2.z + a3.z) * inv;
        meanp[i * 17 + c4 * 4 + 3] = (a0.w + a1.w + a2.w + a3.w) * inv;
    }
    __syncthreads();

    // ---- Phase B: project mean patch onto 16 DCT bases ----
    // thread t: basis m = t>>4, row s = t&15; partial over that row's 16 pixels.
    {
        const int m = t >> 4;
        const int s = t & 15;
        const float* brow = bases + (size_t)m * (PH * PW) + (size_t)s * PW;
        float partial = 0.f;
#pragma unroll
        for (int k = 0; k < 16; ++k)
            partial += meanp[s * 17 + k] * brow[k];
        // reduce across the 16-lane subgroup (xor masks stay inside the group)
        partial += __shfl_xor(partial, 1);
        partial += __shfl_xor(partial, 2);
        partial += __shfl_xor(partial, 4);
        partial += __shfl_xor(partial, 8);
        if (s == 0) coef[m] = partial;
    }
    __syncthreads();

    // ---- Phase C: broadcast each coefficient over its 16x16 footprint ----
    // thread t: plane m = t>>4, patch row r = t&15 -> one 16-float row.
    {
        const int m = t >> 4;
        const int r = t & 15;
        const float cv = coef[m];
        float4 v4 = {cv, cv, cv, cv};
        float* op = out + ((size_t)b * M_ + m) * plane
                        + (size_t)(hp * PH + r) * W_ + (size_t)(wp * PW);
        *(float4*)(op + 0)  = v4;
        *(float4*)(op + 4)  = v4;
        *(float4*)(op + 8)  = v4;
        *(float4*)(op + 12) = v4;
    }
}

extern "C" void kernel_launch(void* const* d_in, const int* in_sizes, int n_in,
                              void* d_out, int out_size, void* d_ws, size_t ws_size,
                              hipStream_t stream) {
    const float* x     = (const float*)d_in[0];
    const float* bases = (const float*)d_in[1];
    float* out         = (float*)d_out;

    const int nblocks = B_ * HP * WP;  // 3136
    dct_patch_fused<<<nblocks, 256, 0, stream>>>(x, bases, out);
}